// Round 3
// baseline (7897.632 us; speedup 1.0000x reference)
//
#include <hip/hip_runtime.h>
#include <hip/hip_cooperative_groups.h>

namespace cg = cooperative_groups;

typedef unsigned short u16;
typedef unsigned int   u32;

#define B_    128
#define N_    8192
#define HD_   256
#define X_    768          // 3*HD
#define T_    10
#define SEGS_ 8
#define SEGROWS_ 1024      // N_/SEGS_
#define PAIRS_ (B_*SEGS_)  // 1024

// ---- persistent per-call state in device globals ----
__device__ float g_h[B_*HD_];
__device__ float g_c[B_*HD_];
__device__ float g_q[B_*HD_];
__device__ float g_pval[B_*SEGS_*3];
__device__ int   g_pidx[B_*SEGS_*3];
__device__ int   g_isf32;

struct P {
  const void *enc, *h0, *c0, *x0, *Wih, *bih, *Whh, *bhh, *Wq, *bq;
  void* out;
};

__device__ __forceinline__ float bf2f(u16 u){ return __uint_as_float(((u32)u)<<16); }
__device__ __forceinline__ float lo2f(u32 w){ return __uint_as_float(w<<16); }
__device__ __forceinline__ float hi2f(u32 w){ return __uint_as_float(w & 0xffff0000u); }
__device__ __forceinline__ u16 f2bf(float f){
  u32 u = __float_as_uint(f);
  u32 r = u + 0x7fffu + ((u>>16)&1u);   // RNE
  return (u16)(r>>16);
}

template<bool F32>
__device__ __forceinline__ float ld1(const void* p, size_t i){
  if constexpr (F32) return ((const float*)p)[i];
  else               return bf2f(((const u16*)p)[i]);
}

template<bool F32>
__device__ __forceinline__ void st1(void* p, size_t i, float v){
  if constexpr (F32) ((float*)p)[i] = v;
  else               ((u16*)p)[i]   = f2bf(v);
}

template<bool F32>
__device__ __forceinline__ void ld8(const void* p, size_t i, float* o){
  if constexpr (F32){
    const float4* q = (const float4*)((const float*)p + i);
    float4 a = q[0], b = q[1];
    o[0]=a.x; o[1]=a.y; o[2]=a.z; o[3]=a.w;
    o[4]=b.x; o[5]=b.y; o[6]=b.z; o[7]=b.w;
  } else {
    uint4 u = *(const uint4*)((const u16*)p + i);
    o[0]=lo2f(u.x); o[1]=hi2f(u.x); o[2]=lo2f(u.y); o[3]=hi2f(u.y);
    o[4]=lo2f(u.z); o[5]=hi2f(u.z); o[6]=lo2f(u.w); o[7]=hi2f(u.w);
  }
}

// top-3 insert, jax.lax.top_k tie-break (equal value -> lower index first)
__device__ __forceinline__ void t3ins(float v,int i,
    float&v0,int&i0,float&v1,int&i1,float&v2,int&i2){
  if (v>v0 || (v==v0 && i<i0)) { v2=v1;i2=i1; v1=v0;i1=i0; v0=v;i0=i; }
  else if (v>v1 || (v==v1 && i<i1)) { v2=v1;i2=i1; v1=v;i1=i; }
  else if (v>v2 || (v==v2 && i<i2)) { v2=v;i2=i; }
}

// ---- dtype probe ----
__global__ void k_probe(const void* enc){
  const int lane = threadIdx.x;           // 64 threads
  const u16 u = ((const u16*)enc)[lane*2];
  const float a = fabsf(bf2f(u));
  const bool inr = (a >= 0.0009765625f) && (a <= 1024.0f);
  unsigned long long m = __ballot(inr ? 1 : 0);
  if (lane==0) g_isf32 = (__popcll(m) < 32) ? 1 : 0;
}

// ---- per-block LSTM body for batch b (256 threads) ----
template<bool F32>
__device__ void lstm_b(const P& p, int t, int b)
{
  const int d = threadIdx.x;
  __shared__ float xs[X_];
  __shared__ float hs[HD_];
  __shared__ float hn[HD_];
  __shared__ int   idx3[3];

  float cd;
  if (t == 0){
    for (int i=d;i<X_;i+=256) xs[i] = ld1<F32>(p.x0, (size_t)b*X_+i);
    hs[d] = ld1<F32>(p.h0, (size_t)b*HD_+d);
    cd    = ld1<F32>(p.c0, (size_t)b*HD_+d);
  } else {
    if (d==0){
      float v0=-3.4e38f,v1=-3.4e38f,v2=-3.4e38f; int i0=-1,i1=-1,i2=-1;
      const float* pv = g_pval + b*SEGS_*3;
      const int*   pi = g_pidx + b*SEGS_*3;
      for (int s=0;s<SEGS_*3;s++) t3ins(pv[s],pi[s],v0,i0,v1,i1,v2,i2);
      idx3[0]=i0; idx3[1]=i1; idx3[2]=i2;
      const size_t ib = (size_t)T_*B_*N_ + (size_t)(t-1)*B_*3 + (size_t)b*3;
      st1<F32>(p.out, ib+0, (float)i0);
      st1<F32>(p.out, ib+1, (float)i1);
      st1<F32>(p.out, ib+2, (float)i2);
    }
    __syncthreads();
    #pragma unroll
    for (int j=0;j<3;j++){
      int jj = idx3[j]; jj = jj<0 ? 0 : (jj>N_-1 ? N_-1 : jj);   // crash guard
      xs[j*HD_+d] = ld1<F32>(p.enc, ((size_t)b*N_ + jj)*HD_ + d);
    }
    hs[d] = g_h[b*HD_+d];
    cd    = g_c[b*HD_+d];
  }
  __syncthreads();

  float g4[4];
  #pragma unroll
  for (int gi=0;gi<4;gi++){
    const int row = gi*HD_ + d;
    float acc = ld1<F32>(p.bih,row) + ld1<F32>(p.bhh,row);
    #pragma unroll 4
    for (int kk=0;kk<X_/8;kk++){
      float w[8]; ld8<F32>(p.Wih, (size_t)row*X_ + kk*8, w);
      #pragma unroll
      for (int j=0;j<8;j++) acc = fmaf(xs[kk*8+j], w[j], acc);
    }
    #pragma unroll 4
    for (int kk=0;kk<HD_/8;kk++){
      float w[8]; ld8<F32>(p.Whh, (size_t)row*HD_ + kk*8, w);
      #pragma unroll
      for (int j=0;j<8;j++) acc = fmaf(hs[kk*8+j], w[j], acc);
    }
    g4[gi]=acc;
  }
  const float sig_i = 1.f/(1.f+expf(-g4[0]));
  const float sig_f = 1.f/(1.f+expf(-g4[1]));
  const float tan_g = tanhf(g4[2]);
  const float sig_o = 1.f/(1.f+expf(-g4[3]));
  const float cn = sig_f*cd + sig_i*tan_g;
  const float hv = sig_o*tanhf(cn);
  g_c[b*HD_+d]=cn; g_h[b*HD_+d]=hv; hn[d]=hv;
  __syncthreads();

  float acc = ld1<F32>(p.bq,d);
  #pragma unroll 4
  for (int kk=0;kk<HD_/8;kk++){
    float w[8]; ld8<F32>(p.Wq, (size_t)d*HD_ + kk*8, w);
    #pragma unroll
    for (int j=0;j<8;j++) acc = fmaf(hn[kk*8+j], w[j], acc);
  }
  g_q[b*HD_+d]=acc;
}

// ---- per-block logits body for (b, seg): 1024 rows (256 threads) ----
template<bool F32>
__device__ void logits_b(const P& p, int t, int b, int seg)
{
  const int tid  = threadIdx.x;
  const int wave = tid>>6;
  const int lane = tid&63;
  const int kl   = lane&31;
  const int half = lane>>5;

  float qv[8];
  const float* qb = g_q + b*HD_ + kl*8;
  #pragma unroll
  for (int j=0;j<8;j++) qv[j]=qb[j];

  float v0=-3.4e38f,v1=-3.4e38f,v2=-3.4e38f; int i0=-1,i1=-1,i2=-1;
  const size_t rowbase = (size_t)b*N_ + (size_t)seg*SEGROWS_;
  const size_t obase   = (size_t)t*B_*N_ + rowbase;

  #pragma unroll 2
  for (int it=0; it<SEGROWS_/8; ++it){   // 128 iters: 4 waves x 2 halves
    const int n = (it*4 + wave)*2 + half;
    float w[8]; ld8<F32>(p.enc, (rowbase + n)*HD_ + kl*8, w);
    float acc =       qv[0]*w[0];
    acc = fmaf(qv[1], w[1], acc);
    acc = fmaf(qv[2], w[2], acc);
    acc = fmaf(qv[3], w[3], acc);
    acc = fmaf(qv[4], w[4], acc);
    acc = fmaf(qv[5], w[5], acc);
    acc = fmaf(qv[6], w[6], acc);
    acc = fmaf(qv[7], w[7], acc);
    #pragma unroll
    for (int off=16; off>=1; off>>=1)
      acc += __shfl_xor(acc, off, 64);   // stays within each 32-lane half
    if (kl==0) st1<F32>(p.out, obase + n, acc);
    t3ins(acc, seg*SEGROWS_+n, v0,i0,v1,i1,v2,i2);
  }

  __shared__ float sv[8][3];
  __shared__ int   si[8][3];
  if (kl==0){
    const int slot = wave*2+half;
    sv[slot][0]=v0; sv[slot][1]=v1; sv[slot][2]=v2;
    si[slot][0]=i0; si[slot][1]=i1; si[slot][2]=i2;
  }
  __syncthreads();
  if (tid==0){
    float w0=-3.4e38f,w1=-3.4e38f,w2=-3.4e38f; int j0=-1,j1=-1,j2=-1;
    for (int s=0;s<8;s++)
      for (int k=0;k<3;k++)
        t3ins(sv[s][k],si[s][k],w0,j0,w1,j1,w2,j2);
    float* pv = g_pval + (b*SEGS_+seg)*3;
    int*   pi = g_pidx + (b*SEGS_+seg)*3;
    pv[0]=w0; pv[1]=w1; pv[2]=w2;
    pi[0]=j0; pi[1]=j1; pi[2]=j2;
  }
  __syncthreads();   // protect sv/si reuse across grid-stride iterations
}

// ---- final idx merge for batch b ----
template<bool F32>
__device__ void final_b(const P& p, int b)
{
  if (threadIdx.x==0){
    float v0=-3.4e38f,v1=-3.4e38f,v2=-3.4e38f; int i0=-1,i1=-1,i2=-1;
    const float* pv = g_pval + b*SEGS_*3;
    const int*   pi = g_pidx + b*SEGS_*3;
    for (int s=0;s<SEGS_*3;s++) t3ins(pv[s],pi[s],v0,i0,v1,i1,v2,i2);
    const size_t ib = (size_t)T_*B_*N_ + (size_t)(T_-1)*B_*3 + (size_t)b*3;
    st1<F32>(p.out, ib+0, (float)i0);
    st1<F32>(p.out, ib+1, (float)i1);
    st1<F32>(p.out, ib+2, (float)i2);
  }
}

// ---- fused cooperative kernel ----
template<bool F32>
__device__ void run_all(const P& p)
{
  cg::grid_group grid = cg::this_grid();
  for (int t=0;t<T_;t++){
    for (int b=blockIdx.x; b<B_; b+=gridDim.x)
      lstm_b<F32>(p, t, b);
    grid.sync();
    for (int pr=blockIdx.x; pr<PAIRS_; pr+=gridDim.x)
      logits_b<F32>(p, t, pr>>3, pr&7);
    grid.sync();
  }
  for (int b=blockIdx.x; b<B_; b+=gridDim.x)
    final_b<F32>(p, b);
}

__global__ __launch_bounds__(256) void k_all(P p)
{
  if (g_isf32) run_all<true >(p);
  else         run_all<false>(p);
}

// ---- fallback multi-kernel path (round-2 proven), same bodies ----
__global__ __launch_bounds__(256) void k_lstm(P p, int t)
{
  if (g_isf32) lstm_b<true >(p, t, blockIdx.x);
  else         lstm_b<false>(p, t, blockIdx.x);
}

__global__ __launch_bounds__(256) void k_logits(P p, int t)
{
  if (g_isf32) logits_b<true >(p, t, blockIdx.y, blockIdx.x);
  else         logits_b<false>(p, t, blockIdx.y, blockIdx.x);
}

__global__ void k_final(P p)
{
  if (g_isf32) final_b<true >(p, blockIdx.x);
  else         final_b<false>(p, blockIdx.x);
}

extern "C" void kernel_launch(void* const* d_in, const int* in_sizes, int n_in,
                              void* d_out, int out_size, void* d_ws, size_t ws_size,
                              hipStream_t stream)
{
  (void)in_sizes; (void)n_in; (void)out_size; (void)d_ws; (void)ws_size;
  P p;
  p.enc = d_in[0];
  p.h0  = d_in[1];
  p.c0  = d_in[2];
  // d_in[3] end_node_embed: unused in prediction mode
  p.x0  = d_in[4];
  p.Wih = d_in[5];
  p.bih = d_in[6];
  p.Whh = d_in[7];
  p.bhh = d_in[8];
  p.Wq  = d_in[9];
  p.bq  = d_in[10];
  // d_in[11] max_steps == 10 (fixed by setup_inputs)
  p.out = d_out;

  k_probe<<<dim3(1),dim3(64),0,stream>>>(p.enc);

  // Cooperative single-dispatch path (grid sized by occupancy, grid-stride safe).
  int occ = 0;
  hipError_t oe = hipOccupancyMaxActiveBlocksPerMultiprocessor(&occ, k_all, 256, 0);
  bool done = false;
  if (oe == hipSuccess && occ > 0){
    int nb = occ * 256;                  // 256 CUs on MI355X
    if (nb > PAIRS_) nb = PAIRS_;
    if (nb >= 128){
      void* args[] = { (void*)&p };
      hipError_t le = hipLaunchCooperativeKernel((void*)k_all, dim3(nb), dim3(256),
                                                 args, 0, stream);
      done = (le == hipSuccess);
    }
  }

  if (!done){
    for (int t=0;t<T_;t++){
      k_lstm  <<<dim3(B_),        dim3(256),0,stream>>>(p, t);
      k_logits<<<dim3(SEGS_,B_),  dim3(256),0,stream>>>(p, t);
    }
    k_final<<<dim3(B_),dim3(64),0,stream>>>(p);
  }
}

// Round 4
// 4128.730 us; speedup vs baseline: 1.9128x; 1.9128x over previous
//
#include <hip/hip_runtime.h>

typedef unsigned short u16;
typedef unsigned int   u32;

#define B_    128
#define N_    8192
#define HD_   256
#define X_    768          // 3*HD
#define T_    10
#define SEGS_ 16
#define SEGROWS_ 512       // N_/SEGS_

// ---- persistent per-call state in device globals ----
__device__ float g_h[B_*HD_];
__device__ float g_c[B_*HD_];
__device__ float g_q[B_*HD_];
__device__ float g_pval[B_*SEGS_*3];
__device__ int   g_pidx[B_*SEGS_*3];
__device__ int   g_isf32;

struct P {
  const void *enc, *h0, *c0, *x0, *Wih, *bih, *Whh, *bhh, *Wq, *bq;
  void* out;
};

__device__ __forceinline__ float bf2f(u16 u){ return __uint_as_float(((u32)u)<<16); }
__device__ __forceinline__ float lo2f(u32 w){ return __uint_as_float(w<<16); }
__device__ __forceinline__ float hi2f(u32 w){ return __uint_as_float(w & 0xffff0000u); }
__device__ __forceinline__ u16 f2bf(float f){
  u32 u = __float_as_uint(f);
  u32 r = u + 0x7fffu + ((u>>16)&1u);   // RNE
  return (u16)(r>>16);
}

template<bool F32>
__device__ __forceinline__ float ld1(const void* p, size_t i){
  if constexpr (F32) return ((const float*)p)[i];
  else               return bf2f(((const u16*)p)[i]);
}

template<bool F32>
__device__ __forceinline__ void st1(void* p, size_t i, float v){
  if constexpr (F32) ((float*)p)[i] = v;
  else               ((u16*)p)[i]   = f2bf(v);
}

template<bool F32>
__device__ __forceinline__ void ld8(const void* p, size_t i, float* o){
  if constexpr (F32){
    const float4* q = (const float4*)((const float*)p + i);
    float4 a = q[0], b = q[1];
    o[0]=a.x; o[1]=a.y; o[2]=a.z; o[3]=a.w;
    o[4]=b.x; o[5]=b.y; o[6]=b.z; o[7]=b.w;
  } else {
    uint4 u = *(const uint4*)((const u16*)p + i);
    o[0]=lo2f(u.x); o[1]=hi2f(u.x); o[2]=lo2f(u.y); o[3]=hi2f(u.y);
    o[4]=lo2f(u.z); o[5]=hi2f(u.z); o[6]=lo2f(u.w); o[7]=hi2f(u.w);
  }
}

// raw 8-elem tile: bf16 = one uint4; f32 = two uint4
template<bool F32> struct Raw8 { uint4 a; };
template<> struct Raw8<true>   { uint4 a, b; };

template<bool F32>
__device__ __forceinline__ void ldraw(const void* p, size_t i, Raw8<F32>& r){
  if constexpr (F32){
    const uint4* q = (const uint4*)((const float*)p + i);
    r.a = q[0]; r.b = q[1];
  } else {
    r.a = *(const uint4*)((const u16*)p + i);
  }
}

template<bool F32>
__device__ __forceinline__ void cvt8(const Raw8<F32>& r, float* o){
  if constexpr (F32){
    o[0]=__uint_as_float(r.a.x); o[1]=__uint_as_float(r.a.y);
    o[2]=__uint_as_float(r.a.z); o[3]=__uint_as_float(r.a.w);
    o[4]=__uint_as_float(r.b.x); o[5]=__uint_as_float(r.b.y);
    o[6]=__uint_as_float(r.b.z); o[7]=__uint_as_float(r.b.w);
  } else {
    o[0]=lo2f(r.a.x); o[1]=hi2f(r.a.x); o[2]=lo2f(r.a.y); o[3]=hi2f(r.a.y);
    o[4]=lo2f(r.a.z); o[5]=hi2f(r.a.z); o[6]=lo2f(r.a.w); o[7]=hi2f(r.a.w);
  }
}

// top-3 insert, jax.lax.top_k tie-break (equal value -> lower index first)
__device__ __forceinline__ void t3ins(float v,int i,
    float&v0,int&i0,float&v1,int&i1,float&v2,int&i2){
  if (v>v0 || (v==v0 && i<i0)) { v2=v1;i2=i1; v1=v0;i1=i0; v0=v;i0=i; }
  else if (v>v1 || (v==v1 && i<i1)) { v2=v1;i2=i1; v1=v;i1=i; }
  else if (v>v2 || (v==v2 && i<i2)) { v2=v;i2=i; }
}

// ---- dtype probe ----
__global__ void k_probe(const void* enc){
  const int lane = threadIdx.x;           // 64 threads
  const u16 u = ((const u16*)enc)[lane*2];
  const float a = fabsf(bf2f(u));
  const bool inr = (a >= 0.0009765625f) && (a <= 1024.0f);
  unsigned long long m = __ballot(inr ? 1 : 0);
  if (lane==0) g_isf32 = (__popcll(m) < 32) ? 1 : 0;
}

// ---- K1: merge prev partials -> idx output + gather x, LSTM, query ----
template<bool F32>
__device__ void lstm_b(const P& p, int t, int b)
{
  const int d = threadIdx.x;
  __shared__ float xs[X_];
  __shared__ float hs[HD_];
  __shared__ float hn[HD_];
  __shared__ int   idx3[3];

  float cd;
  if (t == 0){
    for (int i=d;i<X_;i+=256) xs[i] = ld1<F32>(p.x0, (size_t)b*X_+i);
    hs[d] = ld1<F32>(p.h0, (size_t)b*HD_+d);
    cd    = ld1<F32>(p.c0, (size_t)b*HD_+d);
  } else {
    if (d==0){
      float v0=-3.4e38f,v1=-3.4e38f,v2=-3.4e38f; int i0=-1,i1=-1,i2=-1;
      const float* pv = g_pval + b*SEGS_*3;
      const int*   pi = g_pidx + b*SEGS_*3;
      for (int s=0;s<SEGS_*3;s++) t3ins(pv[s],pi[s],v0,i0,v1,i1,v2,i2);
      idx3[0]=i0; idx3[1]=i1; idx3[2]=i2;
      const size_t ib = (size_t)T_*B_*N_ + (size_t)(t-1)*B_*3 + (size_t)b*3;
      st1<F32>(p.out, ib+0, (float)i0);
      st1<F32>(p.out, ib+1, (float)i1);
      st1<F32>(p.out, ib+2, (float)i2);
    }
    __syncthreads();
    #pragma unroll
    for (int j=0;j<3;j++){
      int jj = idx3[j]; jj = jj<0 ? 0 : (jj>N_-1 ? N_-1 : jj);   // crash guard
      xs[j*HD_+d] = ld1<F32>(p.enc, ((size_t)b*N_ + jj)*HD_ + d);
    }
    hs[d] = g_h[b*HD_+d];
    cd    = g_c[b*HD_+d];
  }
  __syncthreads();

  float g4[4];
  #pragma unroll
  for (int gi=0;gi<4;gi++){
    const int row = gi*HD_ + d;
    float acc = ld1<F32>(p.bih,row) + ld1<F32>(p.bhh,row);
    #pragma unroll 4
    for (int kk=0;kk<X_/8;kk++){
      float w[8]; ld8<F32>(p.Wih, (size_t)row*X_ + kk*8, w);
      #pragma unroll
      for (int j=0;j<8;j++) acc = fmaf(xs[kk*8+j], w[j], acc);
    }
    #pragma unroll 4
    for (int kk=0;kk<HD_/8;kk++){
      float w[8]; ld8<F32>(p.Whh, (size_t)row*HD_ + kk*8, w);
      #pragma unroll
      for (int j=0;j<8;j++) acc = fmaf(hs[kk*8+j], w[j], acc);
    }
    g4[gi]=acc;
  }
  const float sig_i = 1.f/(1.f+expf(-g4[0]));
  const float sig_f = 1.f/(1.f+expf(-g4[1]));
  const float tan_g = tanhf(g4[2]);
  const float sig_o = 1.f/(1.f+expf(-g4[3]));
  const float cn = sig_f*cd + sig_i*tan_g;
  const float hv = sig_o*tanhf(cn);
  g_c[b*HD_+d]=cn; g_h[b*HD_+d]=hv; hn[d]=hv;
  __syncthreads();

  float acc = ld1<F32>(p.bq,d);
  #pragma unroll 4
  for (int kk=0;kk<HD_/8;kk++){
    float w[8]; ld8<F32>(p.Wq, (size_t)d*HD_ + kk*8, w);
    #pragma unroll
    for (int j=0;j<8;j++) acc = fmaf(hn[kk*8+j], w[j], acc);
  }
  g_q[b*HD_+d]=acc;
}

__global__ __launch_bounds__(256) void k_lstm(P p, int t)
{
  if (g_isf32) lstm_b<true >(p, t, blockIdx.x);
  else         lstm_b<false>(p, t, blockIdx.x);
}

// ---- K2: logits, MLP-deep version ----
// 8 lanes (octet) per row. Per wave-round: 8 rows x 4 uint4 loads, double-
// buffered -> 4-8 loads in flight. 3 shfl per row-group; logits buffered in
// LDS and flushed coalesced; top-3 candidates masked to octet leaders.
template<bool F32>
__device__ void logits_b(const P& p, int t, int b, int seg)
{
  const int tid  = threadIdx.x;
  const int wave = tid>>6;
  const int lane = tid&63;
  const int oct  = lane>>3;     // which row of the 8
  const int ol   = lane&7;      // position within octet

  __shared__ float lbuf[SEGROWS_];
  __shared__ float sv[4][3];
  __shared__ int   si[4][3];

  // q fragments: qv[c][j] = q[b][ol*8 + c*64 + j]
  float qv[4][8];
  #pragma unroll
  for (int c=0;c<4;c++){
    const float* qp = g_q + b*HD_ + ol*8 + c*64;
    #pragma unroll
    for (int j=0;j<8;j++) qv[c][j]=qp[j];
  }

  const size_t segrow = (size_t)b*N_ + (size_t)seg*SEGROWS_;  // first row idx
  float v0=-3.4e38f,v1=-3.4e38f,v2=-3.4e38f; int i0=-1,i1=-1,i2=-1;

  Raw8<F32> uA[4], uB[4];

  // row of this (wave,oct) at round k
  #define ROW_OF(k) ((k)*32 + wave*8 + oct)
  #define LOADR(k, u) do{                                                  \
    int r_ = ROW_OF(k) & (SEGROWS_-1);                                     \
    _Pragma("unroll")                                                      \
    for (int c_=0;c_<4;c_++)                                               \
      ldraw<F32>(p.enc, (segrow + r_)*HD_ + ol*8 + c_*64, u[c_]);          \
  }while(0)
  #define PROC(k, u) do{                                                   \
    float acc_ = 0.f;                                                      \
    _Pragma("unroll")                                                      \
    for (int c_=0;c_<4;c_++){                                              \
      float w_[8]; cvt8<F32>(u[c_], w_);                                   \
      _Pragma("unroll")                                                    \
      for (int j_=0;j_<8;j_++) acc_ = fmaf(qv[c_][j_], w_[j_], acc_);      \
    }                                                                      \
    acc_ += __shfl_xor(acc_, 1, 64);                                       \
    acc_ += __shfl_xor(acc_, 2, 64);                                       \
    acc_ += __shfl_xor(acc_, 4, 64);                                       \
    const int r_ = ROW_OF(k);                                              \
    if (ol==0) lbuf[r_] = acc_;                                            \
    const float cs_ = (ol==0) ? acc_ : -3.4e38f;                           \
    const int   ci_ = (ol==0) ? (seg*SEGROWS_ + r_) : -1;                  \
    t3ins(cs_, ci_, v0,i0,v1,i1,v2,i2);                                    \
  }while(0)

  LOADR(0, uA);
  #pragma unroll 1
  for (int k=0;k<16;k+=2){
    LOADR(k+1, uB);
    PROC(k, uA);
    if (k+2 < 16) LOADR(k+2, uA);
    PROC(k+1, uB);
  }
  #undef ROW_OF
  #undef LOADR
  #undef PROC

  // merge top-3 across octet leaders within the wave (lanes 0,8,...,56)
  #pragma unroll
  for (int d=8; d<64; d<<=1){
    float w0=__shfl_xor(v0,d,64), w1=__shfl_xor(v1,d,64), w2=__shfl_xor(v2,d,64);
    int   j0=__shfl_xor(i0,d,64), j1=__shfl_xor(i1,d,64), j2=__shfl_xor(i2,d,64);
    t3ins(w0,j0, v0,i0,v1,i1,v2,i2);
    t3ins(w1,j1, v0,i0,v1,i1,v2,i2);
    t3ins(w2,j2, v0,i0,v1,i1,v2,i2);
  }
  if (lane==0){
    sv[wave][0]=v0; sv[wave][1]=v1; sv[wave][2]=v2;
    si[wave][0]=i0; si[wave][1]=i1; si[wave][2]=i2;
  }
  __syncthreads();

  if (tid==0){
    float w0=-3.4e38f,w1=-3.4e38f,w2=-3.4e38f; int j0=-1,j1=-1,j2=-1;
    for (int s=0;s<4;s++)
      for (int k=0;k<3;k++)
        t3ins(sv[s][k],si[s][k],w0,j0,w1,j1,w2,j2);
    float* pv = g_pval + (b*SEGS_+seg)*3;
    int*   pi = g_pidx + (b*SEGS_+seg)*3;
    pv[0]=w0; pv[1]=w1; pv[2]=w2;
    pi[0]=j0; pi[1]=j1; pi[2]=j2;
  }

  // coalesced logits flush (one shot, full lines)
  const size_t obase = (size_t)t*B_*N_ + segrow;
  if constexpr (F32){
    float2* o2 = (float2*)((float*)p.out + obase);
    o2[tid] = make_float2(lbuf[2*tid], lbuf[2*tid+1]);
  } else {
    u32* o4 = (u32*)((u16*)p.out + obase);
    o4[tid] = (u32)f2bf(lbuf[2*tid]) | ((u32)f2bf(lbuf[2*tid+1])<<16);
  }
}

__global__ __launch_bounds__(256) void k_logits(P p, int t)
{
  if (g_isf32) logits_b<true >(p, t, blockIdx.y, blockIdx.x);
  else         logits_b<false>(p, t, blockIdx.y, blockIdx.x);
}

// ---- K3: final merge for the last step's indices ----
template<bool F32>
__device__ void final_b(const P& p, int b)
{
  if (threadIdx.x==0){
    float v0=-3.4e38f,v1=-3.4e38f,v2=-3.4e38f; int i0=-1,i1=-1,i2=-1;
    const float* pv = g_pval + b*SEGS_*3;
    const int*   pi = g_pidx + b*SEGS_*3;
    for (int s=0;s<SEGS_*3;s++) t3ins(pv[s],pi[s],v0,i0,v1,i1,v2,i2);
    const size_t ib = (size_t)T_*B_*N_ + (size_t)(T_-1)*B_*3 + (size_t)b*3;
    st1<F32>(p.out, ib+0, (float)i0);
    st1<F32>(p.out, ib+1, (float)i1);
    st1<F32>(p.out, ib+2, (float)i2);
  }
}

__global__ void k_final(P p)
{
  if (g_isf32) final_b<true >(p, blockIdx.x);
  else         final_b<false>(p, blockIdx.x);
}

extern "C" void kernel_launch(void* const* d_in, const int* in_sizes, int n_in,
                              void* d_out, int out_size, void* d_ws, size_t ws_size,
                              hipStream_t stream)
{
  (void)in_sizes; (void)n_in; (void)out_size; (void)d_ws; (void)ws_size;
  P p;
  p.enc = d_in[0];
  p.h0  = d_in[1];
  p.c0  = d_in[2];
  // d_in[3] end_node_embed: unused in prediction mode
  p.x0  = d_in[4];
  p.Wih = d_in[5];
  p.bih = d_in[6];
  p.Whh = d_in[7];
  p.bhh = d_in[8];
  p.Wq  = d_in[9];
  p.bq  = d_in[10];
  // d_in[11] max_steps == 10 (fixed by setup_inputs)
  p.out = d_out;

  k_probe<<<dim3(1),dim3(64),0,stream>>>(p.enc);

  for (int t=0;t<T_;t++){
    k_lstm  <<<dim3(B_),       dim3(256),0,stream>>>(p, t);
    k_logits<<<dim3(SEGS_,B_), dim3(256),0,stream>>>(p, t);
  }
  k_final<<<dim3(B_),dim3(64),0,stream>>>(p);
}